// Round 1
// 8432.547 us; speedup vs baseline: 1.2512x; 1.2512x over previous
//
#include <hip/hip_runtime.h>

#define KNBR 32
#define NCELL 4096        // 16^3 Morton cells
#define MAXCHUNK 320      // ceil(20000/64)=313 <= 320
#define FCAP (MAXCHUNK * 64)
#define FT 512            // fps threads: 8 waves
#define NWAVE (FT / 64)
#define NSLOT 40          // chunks per wave: NSLOT * NWAVE = 320 = MAXCHUNK

typedef unsigned long long u64;
typedef unsigned int u32;

// Reference-matching squared distance: ((dx*dx + dy*dy) + dz*dz), no FMA contraction.
__device__ __forceinline__ float sq_dist_nofma(float px, float py, float pz,
                                               float cx, float cy, float cz) {
    float dx = __fsub_rn(px, cx);
    float dy = __fsub_rn(py, cy);
    float dz = __fsub_rn(pz, cz);
    return __fadd_rn(__fadd_rn(__fmul_rn(dx, dx), __fmul_rn(dy, dy)), __fmul_rn(dz, dz));
}

__device__ __forceinline__ unsigned spread4(unsigned v) {
    return (v & 1u) | ((v & 2u) << 2) | ((v & 4u) << 4) | ((v & 8u) << 6);
}

// key = md_bits<<24 | (0x7FFF-orig)<<9 | chunk  (orig<32768, chunk<512).
// u64 max == (max md, then min orig); chunk id rides along. Sentinels -> key 0.
__device__ __forceinline__ u64 pack_key(float md, int orig, int c) {
    return (orig != 0x7fffffff)
        ? (((u64)__float_as_uint(md) << 24) | ((u64)(0x7FFFu - (u32)orig) << 9) | (u64)c)
        : 0ull;
}

// Canonical CDNA wave64 u32 max-reduction: row_shr 1/2/4/8, row_bcast15(rm=0xa),
// row_bcast31(rm=0xc); lane 63 holds the max; readlane broadcasts to all lanes.
// Out-of-pattern lanes contribute 0 (identity for unsigned max; all inputs >= 0).
template<int CTRL, int RM>
__device__ __forceinline__ u32 dppmax_step(u32 v) {
    u32 t = (u32)__builtin_amdgcn_update_dpp(0, (int)v, CTRL, RM, 0xf, false);
    return t > v ? t : v;
}
__device__ __forceinline__ u32 wave_max_u32(u32 v) {
    v = dppmax_step<0x111, 0xf>(v);   // row_shr:1
    v = dppmax_step<0x112, 0xf>(v);   // row_shr:2
    v = dppmax_step<0x114, 0xf>(v);   // row_shr:4
    v = dppmax_step<0x118, 0xf>(v);   // row_shr:8
    v = dppmax_step<0x142, 0xa>(v);   // row_bcast:15 -> rows 1,3
    v = dppmax_step<0x143, 0xc>(v);   // row_bcast:31 -> rows 2,3
    return (u32)__builtin_amdgcn_readlane((int)v, 63);
}

// K1: AoS -> SoA + norms + Morton cell id + within-cell rank (counting-sort pass 1)
__global__ void prep_kernel(const float* __restrict__ coord, int N,
                            float* __restrict__ sx, float* __restrict__ sy,
                            float* __restrict__ sz, float* __restrict__ sn,
                            int* __restrict__ cell, int* __restrict__ rank,
                            int* __restrict__ hist) {
    int i = blockIdx.x * blockDim.x + threadIdx.x;
    if (i < N) {
        float x = coord[3 * i + 0];
        float y = coord[3 * i + 1];
        float z = coord[3 * i + 2];
        sx[i] = x; sy[i] = y; sz[i] = z;
        sn[i] = __fadd_rn(__fadd_rn(__fmul_rn(x, x), __fmul_rn(y, y)), __fmul_rn(z, z));
        int ix = (int)(x * 16.0f); ix = ix < 0 ? 0 : (ix > 15 ? 15 : ix);
        int iy = (int)(y * 16.0f); iy = iy < 0 ? 0 : (iy > 15 ? 15 : iy);
        int iz = (int)(z * 16.0f); iz = iz < 0 ? 0 : (iz > 15 ? 15 : iz);
        unsigned mc = spread4(ix) | (spread4(iy) << 1) | (spread4(iz) << 2);
        cell[i] = (int)mc;
        rank[i] = atomicAdd(&hist[mc], 1);
    }
}

// K2: exclusive scan of 4096-bin histogram
__global__ __launch_bounds__(1024) void scan_kernel(const int* __restrict__ hist,
                                                    int* __restrict__ cellstart) {
    __shared__ int buf[1024];
    int t = threadIdx.x;
    int h0 = hist[4 * t], h1 = hist[4 * t + 1], h2 = hist[4 * t + 2], h3 = hist[4 * t + 3];
    int s = h0 + h1 + h2 + h3;
    buf[t] = s;
    __syncthreads();
    for (int off = 1; off < 1024; off <<= 1) {
        int v = (t >= off) ? buf[t - off] : 0;
        __syncthreads();
        buf[t] += v;
        __syncthreads();
    }
    int ex = buf[t] - s;
    cellstart[4 * t]     = ex;
    cellstart[4 * t + 1] = ex + h0;
    cellstart[4 * t + 2] = ex + h0 + h1;
    cellstart[4 * t + 3] = ex + h0 + h1 + h2;
}

// K3: scatter into Morton order, packed as (x, y, z, orig_idx_bits)
__global__ void scatter_kernel(const float* __restrict__ sx, const float* __restrict__ sy,
                               const float* __restrict__ sz,
                               const int* __restrict__ cell, const int* __restrict__ rank,
                               const int* __restrict__ cellstart, int N,
                               float4* __restrict__ pts) {
    int i = blockIdx.x * blockDim.x + threadIdx.x;
    if (i < N) {
        int pos = cellstart[cell[i]] + rank[i];
        pts[pos] = make_float4(sx[i], sy[i], sz[i], __int_as_float(i));
    }
}

// K3b: sentinel padding
__global__ void pad_kernel(float4* __restrict__ pts, int N, int cap) {
    int i = N + blockIdx.x * blockDim.x + threadIdx.x;
    if (i < cap) pts[i] = make_float4(1e18f, 1e18f, 1e18f, __int_as_float(0x7fffffff));
}

// K3c: per-chunk init — md vs original point 0, chunk sphere, chunk key, winner coords.
__global__ void init_chunk_kernel(const float4* __restrict__ pts,
                                  const float* __restrict__ coord,
                                  float* __restrict__ mdbuf,
                                  float4* __restrict__ spheres,
                                  u64* __restrict__ ckeys,
                                  float4* __restrict__ wxyz_g) {
    int c = blockIdx.x, lane = threadIdx.x;
    int pos = (c << 6) + lane;
    float4 P = pts[pos];
    int orig = __float_as_int(P.w);
    bool real = (orig != 0x7fffffff);
    float c0x = coord[0], c0y = coord[1], c0z = coord[2];
    float d = sq_dist_nofma(P.x, P.y, P.z, c0x, c0y, c0z);
    float m = real ? d : -3e38f;
    mdbuf[pos] = m;
    u64 kself = pack_key(m, orig, c);
    u64 key = kself;
    float mnx = real ? P.x : 1e30f, mxx = real ? P.x : -1e30f;
    float mny = real ? P.y : 1e30f, mxy = real ? P.y : -1e30f;
    float mnz = real ? P.z : 1e30f, mxz = real ? P.z : -1e30f;
    #pragma unroll
    for (int off = 32; off; off >>= 1) {
        u64 k2 = __shfl_xor(key, off, 64);
        if (k2 > key) key = k2;
        mnx = fminf(mnx, __shfl_xor(mnx, off, 64));
        mxx = fmaxf(mxx, __shfl_xor(mxx, off, 64));
        mny = fminf(mny, __shfl_xor(mny, off, 64));
        mxy = fmaxf(mxy, __shfl_xor(mxy, off, 64));
        mnz = fminf(mnz, __shfl_xor(mnz, off, 64));
        mxz = fmaxf(mxz, __shfl_xor(mxz, off, 64));
    }
    if (kself == key) wxyz_g[c] = make_float4(P.x, P.y, P.z, 0.f);  // unique owner lane
    if (lane == 0) {
        float cx = 0.5f * (mnx + mxx), cy = 0.5f * (mny + mxy), cz = 0.5f * (mnz + mxz);
        float ex = (mxx - mnx) * 0.5f, ey = (mxy - mny) * 0.5f, ez = (mxz - mnz) * 0.5f;
        float r = sqrtf(ex * ex + ey * ey + ez * ez) * 1.0001f + 1e-7f;
        spheres[c] = make_float4(cx, cy, cz, r);
        ckeys[c] = key;
    }
}

// K4: chunked FPS, round-13: FULLY REGISTER-RESIDENT point state.
// Each thread of wave w holds NSLOT=40 slots: slot r = chunk r*8+w, lane's point
// pos = chunk*64+lane. Per slot: x,y,z (static), md (mutable), lo = static low-24
// key bits ((0x7FFF-orig)<<9|chunk), lo<0 = sentinel. Eliminates ALL per-chunk
// global loads/stores (pts + mdbuf L2 round-trips) from the serial step loop.
// Per-chunk fast filters: (a) ballot(d<md)==0 -> key untouched, skip;
// (b) winner lane's md unchanged -> max & winner unchanged (mds only decrease),
// skip reduce. Reduce = 2-phase u32 DPP max (md bits, then lo among tied) with
// winner broadcast via readlane (scalar lane id). Permuted ownership as before:
// thread (w, lane) owns chunk lane*8+w; only the 8-entry wwin handoff crosses
// waves, single parity-buffered barrier per step.
__global__ __launch_bounds__(FT, 2)
void fps_kernel(const float4* __restrict__ pts,
                const float* __restrict__ coord,
                const float4* __restrict__ spheres_g, const u64* __restrict__ ckeys_g,
                const float4* __restrict__ wxyz_g,
                int nchunk, int n_dst, int* __restrict__ out_idx) {
    __shared__ u64    wwin[2][NWAVE];
    __shared__ float4 wcoord[2][NWAVE];

    const int tid = threadIdx.x, lane = tid & 63, wv = tid >> 6;
    const int myc = (lane << 3) + wv;      // permuted ownership: chunk -> wave = c & 7

    const float c0x = coord[0], c0y = coord[1], c0z = coord[2];

    // ---- register-resident point state: 5 * NSLOT = 200 VGPRs ----
    float px[NSLOT], py[NSLOT], pz[NSLOT], pmd[NSLOT];
    int   plo[NSLOT];
    #pragma unroll
    for (int r = 0; r < NSLOT; ++r) {
        int c = r * 8 + wv;
        if (c < nchunk) {                           // wave-uniform
            float4 P = pts[(c << 6) + lane];
            int orig = __float_as_int(P.w);
            px[r] = P.x; py[r] = P.y; pz[r] = P.z;
            if (orig != 0x7fffffff) {
                plo[r] = ((0x7FFF - orig) << 9) | c;
                // bit-identical to init_chunk's md -> keys stay consistent
                pmd[r] = sq_dist_nofma(P.x, P.y, P.z, c0x, c0y, c0z);
            } else { plo[r] = -1; pmd[r] = -3e38f; }
        } else { plo[r] = -1; pmd[r] = -3e38f; px[r] = py[r] = pz[r] = 0.f; }
    }

    // ---- per-owned-chunk state (thread (wv,lane) owns chunk myc) ----
    u64 k0 = 0ull;                          // own chunk's key (maxmd | orig | chunk)
    float wx = 0.f, wy = 0.f, wz = 0.f;     // own chunk's winner coords
    int wlane = 0;                          // own chunk's winner LANE within its wave
    float4 S = make_float4(1e18f, 1e18f, 1e18f, 0.f);   // own chunk's sphere
    if (myc < nchunk) {
        k0 = ckeys_g[myc];
        float4 W = wxyz_g[myc];
        wx = W.x; wy = W.y; wz = W.z;
        S = spheres_g[myc];
    }
    // derive winner lane: match k0's static low-24 bits against this wave's plo[r]
    #pragma unroll
    for (int r = 0; r < NSLOT; ++r) {
        u32 lov = (u32)__builtin_amdgcn_readlane((int)(u32)k0, r) & 0xFFFFFFu;
        u64 mk = __ballot(plo[r] >= 0 && (u32)plo[r] == lov);
        if (lane == r && mk) wlane = __ffsll(mk) - 1;
    }

    if (tid == 0) out_idx[0] = 0;
    __syncthreads();

    int par = 1;
    for (int s = 1; s < n_dst; ++s) {
        // A: wave argmax over register keys, 2-phase u32 DPP; owner writes parity slot.
        u32 hi  = (u32)(k0 >> 32);
        u32 mhi = wave_max_u32(hi);
        u32 mlo = wave_max_u32(hi == mhi ? (u32)k0 : 0u);
        u64 k = ((u64)mhi << 32) | mlo;
        if (k0 == k && k0 != 0ull) {        // unique owner (keys embed chunk id)
            wwin[par][wv]   = k;
            wcoord[par][wv] = make_float4(wx, wy, wz, 0.f);
        }
        __syncthreads();                    // the ONLY barrier per step
        u64 kb = wwin[par][0]; int wb = 0;
        #pragma unroll
        for (int w = 1; w < NWAVE; ++w) {
            u64 t2 = wwin[par][w];
            if (t2 > kb) { kb = t2; wb = w; }
        }
        float4 C4 = wcoord[par][wb];
        float ncx = C4.x, ncy = C4.y, ncz = C4.z;
        if (tid == 0) out_idx[s] = (int)(0x7FFFu - (u32)((kb >> 9) & 0x7FFFull));
        par ^= 1;

        // B: prune own chunk (registers only).
        // Pruned: for all p in chunk, d(p,nc) >= D - r > sqrt(maxmd) => no md change.
        // Winner's chunk never pruned (nc inside its own sphere).
        bool act = false;
        if (k0 != 0ull) {
            float maxmd = __uint_as_float((u32)(k0 >> 24));
            float Dx = ncx - S.x, Dy = ncy - S.y, Dz = ncz - S.z;
            float D2 = Dx * Dx + Dy * Dy + Dz * Dz;
            float t0 = sqrtf(maxmd) * 1.0001f + S.w;
            float thr = t0 * t0 * 1.0002f + 1e-12f;
            act = (D2 <= thr);
        }
        u64 m = __ballot(act);              // bit r -> chunk r*8+wv active

        // C: process active slots, all in registers. Static unroll keeps arrays
        // in VGPRs (runtime indexing would scratch-spill). Guard is scalar branch.
        #pragma unroll
        for (int r = 0; r < NSLOT; ++r) {
            if ((m >> r) & 1ull) {
                float d = sq_dist_nofma(px[r], py[r], pz[r], ncx, ncy, ncz);
                bool chg = d < pmd[r];      // sentinels: d=inf, never true
                u64 mchg = __ballot(chg);
                if (mchg) {
                    if (chg) pmd[r] = d;    // fmin(pmd,d) == d when chg
                    // mds only decrease: chunk max/winner can change only if the
                    // winner lane's own md decreased.
                    int wlo = __builtin_amdgcn_readlane(wlane, r);
                    if ((mchg >> wlo) & 1ull) {
                        bool real = plo[r] >= 0;
                        u32 v  = real ? __float_as_uint(pmd[r]) : 0u;
                        u32 mv = wave_max_u32(v);
                        bool tied = real && (v == mv);
                        u32 t2 = wave_max_u32(tied ? (u32)plo[r] : 0u);
                        int wl = __ffsll(__ballot(tied && (u32)plo[r] == t2)) - 1;
                        int low = __builtin_amdgcn_readlane(plo[r], wl);
                        float bx = __uint_as_float((u32)__builtin_amdgcn_readlane(__float_as_int(px[r]), wl));
                        float by = __uint_as_float((u32)__builtin_amdgcn_readlane(__float_as_int(py[r]), wl));
                        float bz = __uint_as_float((u32)__builtin_amdgcn_readlane(__float_as_int(pz[r]), wl));
                        if (lane == r) {    // deliver to owner lane (same wave)
                            k0 = ((u64)mv << 24) | (u32)low;
                            wx = bx; wy = by; wz = bz; wlane = wl;
                        }
                    }
                }
            }
        }
    }
}

// K5: ball query, one wave per dst. First K in-radius src indices in ascending order.
__global__ void ball_kernel(const float* __restrict__ sx, const float* __restrict__ sy,
                            const float* __restrict__ sz, const float* __restrict__ sn,
                            const int* __restrict__ idx,
                            const float* __restrict__ coord, const int* __restrict__ batch,
                            int N, int n_dst,
                            float* __restrict__ out_coord, float* __restrict__ out_esrc,
                            float* __restrict__ out_edst, float* __restrict__ out_deg,
                            float* __restrict__ out_batch,
                            int* __restrict__ nbr_i, int* __restrict__ deg_i) {
    const int d    = blockIdx.x;
    const int lane = threadIdx.x;   // block of 64
    __shared__ int nbr[KNBR];

    const int id = idx[d];
    const float cx = sx[id], cy = sy[id], cz = sz[id];
    const float dn = sn[id];
    const float RR = (float)(0.08 * 0.08);

    int cnt = 0;
    for (int base = 0; base < N && cnt < KNBR; base += 64) {
        int i = base + lane;
        bool in = false;
        if (i < N) {
            float t     = __fmul_rn(sx[i], cx);
            float inner = __fmaf_rn(sy[i], cy, t);
            inner       = __fmaf_rn(sz[i], cz, inner);
            float d2    = __fsub_rn(__fadd_rn(dn, sn[i]), __fmul_rn(2.0f, inner));
            in = (d2 <= RR);
        }
        unsigned long long m = __ballot(in);
        int pos = cnt + __popcll(m & ((1ull << lane) - 1ull));
        if (in && pos < KNBR) nbr[pos] = i;
        cnt += (int)__popcll(m);
    }
    __syncthreads();

    int deg = cnt < KNBR ? cnt : KNBR;
    if (lane < KNBR) {
        int e = (lane < deg) ? nbr[lane] : -1;
        out_esrc[d * KNBR + lane] = (float)e;
        out_edst[d * KNBR + lane] = (float)((lane < deg) ? d : -1);
        nbr_i[d * KNBR + lane] = e;
    }
    if (lane == 0) { out_deg[d] = (float)deg; deg_i[d] = deg; }
    if (lane < 3)  out_coord[d * 3 + lane] = coord[id * 3 + lane];
    if (lane == 3) out_batch[d] = (float)batch[id];
}

// K6: scatter-mean of gathered features. One block per dst, one thread per feature dim.
__global__ void agg_kernel(const float* __restrict__ feat,
                           const int* __restrict__ nbr_i, const int* __restrict__ deg_i,
                           int F, float* __restrict__ out_feat) {
    const int d = blockIdx.x;
    const int t = threadIdx.x;  // F threads
    const int deg = deg_i[d];
    float acc = 0.0f;
    for (int k = 0; k < deg; ++k) {
        int nb = nbr_i[d * KNBR + k];
        acc = __fadd_rn(acc, feat[nb * F + t]);
    }
    float den = (float)(deg > 0 ? deg : 1);
    out_feat[d * F + t] = acc / den;
}

extern "C" void kernel_launch(void* const* d_in, const int* in_sizes, int n_in,
                              void* d_out, int out_size, void* d_ws, size_t ws_size,
                              hipStream_t stream) {
    const float* coord = (const float*)d_in[0];
    const float* feat  = (const float*)d_in[1];
    const int*   batch = (const int*)d_in[2];

    const int N      = in_sizes[0] / 3;
    const int F      = in_sizes[1] / N;
    const int n_dst  = N / 4;                 // RATIO = 0.25
    const int nchunk = (N + 63) / 64;         // 313

    // workspace layout (pts 16B-aligned: 4N floats precede it; N=20000 -> 320000 B)
    float*  sx      = (float*)d_ws;
    float*  sy      = sx + N;
    float*  sz      = sy + N;
    float*  sn      = sz + N;
    float4* pts     = (float4*)(sn + N);      // FCAP packed points
    float4* spheres = pts + FCAP;             // MAXCHUNK
    float4* wxyz_g  = spheres + MAXCHUNK;     // MAXCHUNK winner coords
    float*  mdbuf   = (float*)(wxyz_g + MAXCHUNK);    // FCAP floats
    u64*    ckeys   = (u64*)(mdbuf + FCAP);   // MAXCHUNK (8B-aligned)
    int*    cell      = (int*)(ckeys + MAXCHUNK);
    int*    rank      = cell + N;
    int*    hist      = rank + N;
    int*    cellstart = hist + NCELL;
    int*    idx       = cellstart + NCELL;
    int*    nbr_i     = idx + n_dst;
    int*    deg_i     = nbr_i + n_dst * KNBR;

    // output layout (all float32), reference return order
    float* out     = (float*)d_out;
    float* o_coord = out;                         // n_dst*3
    float* o_feat  = o_coord + (size_t)n_dst * 3; // n_dst*F
    float* o_esrc  = o_feat  + (size_t)n_dst * F; // n_dst*K
    float* o_edst  = o_esrc  + (size_t)n_dst * KNBR;
    float* o_deg   = o_edst  + (size_t)n_dst * KNBR;
    float* o_batch = o_deg   + n_dst;

    hipMemsetAsync(hist, 0, NCELL * sizeof(int), stream);
    prep_kernel<<<(N + 255) / 256, 256, 0, stream>>>(coord, N, sx, sy, sz, sn,
                                                     cell, rank, hist);
    scan_kernel<<<1, 1024, 0, stream>>>(hist, cellstart);
    scatter_kernel<<<(N + 255) / 256, 256, 0, stream>>>(sx, sy, sz, cell, rank,
                                                        cellstart, N, pts);
    pad_kernel<<<(nchunk * 64 - N + 255) / 256, 256, 0, stream>>>(pts, N, nchunk * 64);
    init_chunk_kernel<<<nchunk, 64, 0, stream>>>(pts, coord, mdbuf, spheres, ckeys,
                                                 wxyz_g);
    fps_kernel<<<1, FT, 0, stream>>>(pts, coord, spheres, ckeys, wxyz_g,
                                     nchunk, n_dst, idx);
    ball_kernel<<<n_dst, 64, 0, stream>>>(sx, sy, sz, sn, idx, coord, batch, N, n_dst,
                                          o_coord, o_esrc, o_edst, o_deg, o_batch,
                                          nbr_i, deg_i);
    agg_kernel<<<n_dst, F, 0, stream>>>(feat, nbr_i, deg_i, F, o_feat);
}

// Round 2
// 6763.309 us; speedup vs baseline: 1.5601x; 1.2468x over previous
//
#include <hip/hip_runtime.h>

#define KNBR 32
#define NCELL 4096        // 16^3 Morton cells
#define MAXCHUNK 320      // ceil(20000/64)=313 <= 320
#define FCAP (MAXCHUNK * 64)
#define FT 768            // fps threads: 12 waves
#define NWAVE (FT / 64)   // 12
#define NSLOT 27          // chunks per wave: 27*12 = 324 >= 320
#define NSLOT2 ((NSLOT + 1) / 2)

typedef unsigned long long u64;
typedef unsigned int u32;

// Reference-matching squared distance: ((dx*dx + dy*dy) + dz*dz), no FMA contraction.
__device__ __forceinline__ float sq_dist_nofma(float px, float py, float pz,
                                               float cx, float cy, float cz) {
    float dx = __fsub_rn(px, cx);
    float dy = __fsub_rn(py, cy);
    float dz = __fsub_rn(pz, cz);
    return __fadd_rn(__fadd_rn(__fmul_rn(dx, dx), __fmul_rn(dy, dy)), __fmul_rn(dz, dz));
}

__device__ __forceinline__ unsigned spread4(unsigned v) {
    return (v & 1u) | ((v & 2u) << 2) | ((v & 4u) << 4) | ((v & 8u) << 6);
}

// key = md_bits<<24 | (0x7FFF-orig)<<9 | chunk  (orig<32768, chunk<512).
// u64 max == (max md, then min orig); chunk id rides along. Sentinels -> key 0.
__device__ __forceinline__ u64 pack_key(float md, int orig, int c) {
    return (orig != 0x7fffffff)
        ? (((u64)__float_as_uint(md) << 24) | ((u64)(0x7FFFu - (u32)orig) << 9) | (u64)c)
        : 0ull;
}

// Canonical CDNA wave64 u32 max-reduction: row_shr 1/2/4/8, row_bcast15(rm=0xa),
// row_bcast31(rm=0xc); lane 63 holds the max; readlane broadcasts to all lanes.
// Out-of-pattern lanes contribute 0 (identity for unsigned max; all inputs >= 0).
template<int CTRL, int RM>
__device__ __forceinline__ u32 dppmax_step(u32 v) {
    u32 t = (u32)__builtin_amdgcn_update_dpp(0, (int)v, CTRL, RM, 0xf, false);
    return t > v ? t : v;
}
__device__ __forceinline__ u32 wave_max_u32(u32 v) {
    v = dppmax_step<0x111, 0xf>(v);   // row_shr:1
    v = dppmax_step<0x112, 0xf>(v);   // row_shr:2
    v = dppmax_step<0x114, 0xf>(v);   // row_shr:4
    v = dppmax_step<0x118, 0xf>(v);   // row_shr:8
    v = dppmax_step<0x142, 0xa>(v);   // row_bcast:15 -> rows 1,3
    v = dppmax_step<0x143, 0xc>(v);   // row_bcast:31 -> rows 2,3
    return (u32)__builtin_amdgcn_readlane((int)v, 63);
}

// K1: AoS -> SoA + norms + Morton cell id + within-cell rank (counting-sort pass 1)
__global__ void prep_kernel(const float* __restrict__ coord, int N,
                            float* __restrict__ sx, float* __restrict__ sy,
                            float* __restrict__ sz, float* __restrict__ sn,
                            int* __restrict__ cell, int* __restrict__ rank,
                            int* __restrict__ hist) {
    int i = blockIdx.x * blockDim.x + threadIdx.x;
    if (i < N) {
        float x = coord[3 * i + 0];
        float y = coord[3 * i + 1];
        float z = coord[3 * i + 2];
        sx[i] = x; sy[i] = y; sz[i] = z;
        sn[i] = __fadd_rn(__fadd_rn(__fmul_rn(x, x), __fmul_rn(y, y)), __fmul_rn(z, z));
        int ix = (int)(x * 16.0f); ix = ix < 0 ? 0 : (ix > 15 ? 15 : ix);
        int iy = (int)(y * 16.0f); iy = iy < 0 ? 0 : (iy > 15 ? 15 : iy);
        int iz = (int)(z * 16.0f); iz = iz < 0 ? 0 : (iz > 15 ? 15 : iz);
        unsigned mc = spread4(ix) | (spread4(iy) << 1) | (spread4(iz) << 2);
        cell[i] = (int)mc;
        rank[i] = atomicAdd(&hist[mc], 1);
    }
}

// K2: exclusive scan of 4096-bin histogram
__global__ __launch_bounds__(1024) void scan_kernel(const int* __restrict__ hist,
                                                    int* __restrict__ cellstart) {
    __shared__ int buf[1024];
    int t = threadIdx.x;
    int h0 = hist[4 * t], h1 = hist[4 * t + 1], h2 = hist[4 * t + 2], h3 = hist[4 * t + 3];
    int s = h0 + h1 + h2 + h3;
    buf[t] = s;
    __syncthreads();
    for (int off = 1; off < 1024; off <<= 1) {
        int v = (t >= off) ? buf[t - off] : 0;
        __syncthreads();
        buf[t] += v;
        __syncthreads();
    }
    int ex = buf[t] - s;
    cellstart[4 * t]     = ex;
    cellstart[4 * t + 1] = ex + h0;
    cellstart[4 * t + 2] = ex + h0 + h1;
    cellstart[4 * t + 3] = ex + h0 + h1 + h2;
}

// K3: scatter into Morton order, packed as (x, y, z, orig_idx_bits)
__global__ void scatter_kernel(const float* __restrict__ sx, const float* __restrict__ sy,
                               const float* __restrict__ sz,
                               const int* __restrict__ cell, const int* __restrict__ rank,
                               const int* __restrict__ cellstart, int N,
                               float4* __restrict__ pts) {
    int i = blockIdx.x * blockDim.x + threadIdx.x;
    if (i < N) {
        int pos = cellstart[cell[i]] + rank[i];
        pts[pos] = make_float4(sx[i], sy[i], sz[i], __int_as_float(i));
    }
}

// K3b: sentinel padding
__global__ void pad_kernel(float4* __restrict__ pts, int N, int cap) {
    int i = N + blockIdx.x * blockDim.x + threadIdx.x;
    if (i < cap) pts[i] = make_float4(1e18f, 1e18f, 1e18f, __int_as_float(0x7fffffff));
}

// K3c: per-chunk init — md vs original point 0, chunk sphere, chunk key, winner coords.
__global__ void init_chunk_kernel(const float4* __restrict__ pts,
                                  const float* __restrict__ coord,
                                  float* __restrict__ mdbuf,
                                  float4* __restrict__ spheres,
                                  u64* __restrict__ ckeys,
                                  float4* __restrict__ wxyz_g) {
    int c = blockIdx.x, lane = threadIdx.x;
    int pos = (c << 6) + lane;
    float4 P = pts[pos];
    int orig = __float_as_int(P.w);
    bool real = (orig != 0x7fffffff);
    float c0x = coord[0], c0y = coord[1], c0z = coord[2];
    float d = sq_dist_nofma(P.x, P.y, P.z, c0x, c0y, c0z);
    float m = real ? d : -3e38f;
    mdbuf[pos] = m;
    u64 kself = pack_key(m, orig, c);
    u64 key = kself;
    float mnx = real ? P.x : 1e30f, mxx = real ? P.x : -1e30f;
    float mny = real ? P.y : 1e30f, mxy = real ? P.y : -1e30f;
    float mnz = real ? P.z : 1e30f, mxz = real ? P.z : -1e30f;
    #pragma unroll
    for (int off = 32; off; off >>= 1) {
        u64 k2 = __shfl_xor(key, off, 64);
        if (k2 > key) key = k2;
        mnx = fminf(mnx, __shfl_xor(mnx, off, 64));
        mxx = fmaxf(mxx, __shfl_xor(mxx, off, 64));
        mny = fminf(mny, __shfl_xor(mny, off, 64));
        mxy = fmaxf(mxy, __shfl_xor(mxy, off, 64));
        mnz = fminf(mnz, __shfl_xor(mnz, off, 64));
        mxz = fmaxf(mxz, __shfl_xor(mxz, off, 64));
    }
    if (kself == key) wxyz_g[c] = make_float4(P.x, P.y, P.z, 0.f);  // unique owner lane
    if (lane == 0) {
        float cx = 0.5f * (mnx + mxx), cy = 0.5f * (mny + mxy), cz = 0.5f * (mnz + mxz);
        float ex = (mxx - mnx) * 0.5f, ey = (mxy - mny) * 0.5f, ez = (mxz - mnz) * 0.5f;
        float r = sqrtf(ex * ex + ey * ey + ez * ez) * 1.0001f + 1e-7f;
        spheres[c] = make_float4(cx, cy, cz, r);
        ckeys[c] = key;
    }
}

// K4: chunked FPS, round-14: 12 waves x 27 slots, trimmed register state
// (px,py,pz,pmd + packed 16-bit orig = ~125 VGPR demand vs 168 cap), sentinel
// md = 0.0f (identity for unsigned max -> no "real" mask in the reduce),
// unique-winner shortcuts in phase A and in the per-chunk reduce (second DPP
// chain only on exact bit-ties), prune threshold hoisted pre-barrier, and a
// tree-structured 12-entry cross-wave scan (winner wave = chunk_id % NWAVE,
// recovered from the key's low bits -> no index tracking in the tree).
// Ownership: chunk c -> wave c%NWAVE, slot c/NWAVE, owner lane = slot; all
// per-chunk work stays inside one wave; only the NWAVE-entry wwin handoff
// crosses waves, single parity-buffered barrier per step.
__global__ __launch_bounds__(FT, 3)
void fps_kernel(const float4* __restrict__ pts,
                const float* __restrict__ coord,
                const float4* __restrict__ spheres_g, const u64* __restrict__ ckeys_g,
                const float4* __restrict__ wxyz_g,
                int nchunk, int n_dst, int* __restrict__ out_idx) {
    __shared__ u64    wwin[2][NWAVE];
    __shared__ float4 wcoord[2][NWAVE];

    const int tid = threadIdx.x, lane = tid & 63, wv = tid / 64;
    const int myc = lane * NWAVE + wv;     // lane r of wave wv owns chunk r*NWAVE+wv

    const float c0x = coord[0], c0y = coord[1], c0z = coord[2];

    // ---- register-resident point state ----
    float px[NSLOT], py[NSLOT], pz[NSLOT], pmd[NSLOT];
    u32   po16[NSLOT2];                    // packed 16-bit orig; 0xFFFF = sentinel
    #pragma unroll
    for (int h = 0; h < NSLOT2; ++h) po16[h] = 0xFFFFFFFFu;
    #pragma unroll
    for (int r = 0; r < NSLOT; ++r) {
        int c = r * NWAVE + wv;
        float x = 0.f, y = 0.f, z = 0.f, md = 0.f;
        u32 o = 0xFFFFu;
        if (c < nchunk) {                           // wave-uniform
            float4 P = pts[(c << 6) + lane];
            int orig = __float_as_int(P.w);
            x = P.x; y = P.y; z = P.z;
            if (orig != 0x7fffffff) {
                o = (u32)orig;
                // bit-identical to init_chunk's md -> keys stay consistent
                md = sq_dist_nofma(x, y, z, c0x, c0y, c0z);
            }
        }
        px[r] = x; py[r] = y; pz[r] = z; pmd[r] = md;   // sentinel md = 0 (max identity)
        if (r & 1) po16[r / 2] = (po16[r / 2] & 0x0000FFFFu) | (o << 16);
        else       po16[r / 2] = (po16[r / 2] & 0xFFFF0000u) | o;
    }

    // ---- per-owned-chunk state (lane r of wave wv owns chunk r*NWAVE+wv) ----
    u64 k0 = 0ull;                          // own chunk's key (maxmd | orig | chunk)
    float wx = 0.f, wy = 0.f, wz = 0.f;     // own chunk's winner coords
    int wlane = 0;                          // own chunk's winner LANE within its wave
    float4 S = make_float4(1e18f, 1e18f, 1e18f, 0.f);   // own chunk's sphere
    if (lane < NSLOT && myc < nchunk) {
        k0 = ckeys_g[myc];
        float4 W = wxyz_g[myc];
        wx = W.x; wy = W.y; wz = W.z;
        S = spheres_g[myc];
    }
    // derive winner lane: match k0's static low-24 bits against reconstructed plo
    #pragma unroll
    for (int r = 0; r < NSLOT; ++r) {
        u32 lov = (u32)__builtin_amdgcn_readlane((int)(u32)k0, r) & 0xFFFFFFu;
        u32 o = (po16[r / 2] >> (16 * (r & 1))) & 0xFFFFu;
        u32 pl = ((0x7FFFu - o) << 9) | (u32)(r * NWAVE + wv);
        u64 mk = __ballot(o != 0xFFFFu && pl == lov);
        if (lane == r && mk) wlane = __ffsll(mk) - 1;
    }

    if (tid == 0) out_idx[0] = 0;
    __syncthreads();

    int par = 1;
    for (int s = 1; s < n_dst; ++s) {
        // A: wave argmax over k0. One DPP chain on the hi word; unique-winner
        // shortcut grabs the lo word with a single readlane (tie ~0.3% of steps).
        u32 hi  = (u32)(k0 >> 32);
        u32 mhi = wave_max_u32(hi);
        u64 tbA = __ballot(hi == mhi);
        u32 mlo;
        if (__popcll(tbA) == 1) {
            int wlA = __ffsll(tbA) - 1;
            mlo = (u32)__builtin_amdgcn_readlane((int)(u32)k0, wlA);
        } else {
            mlo = wave_max_u32(hi == mhi ? (u32)k0 : 0u);
        }
        u64 k = ((u64)mhi << 32) | mlo;
        if (k0 == k && k0 != 0ull) {        // unique owner (keys embed chunk id)
            wwin[par][wv]   = k;
            wcoord[par][wv] = make_float4(wx, wy, wz, 0.f);
        }
        // prune threshold: depends only on own k0/S -> hoisted off the
        // post-barrier critical path
        float thr = -1.0f;
        if (k0 != 0ull) {
            float maxmd = __uint_as_float((u32)(k0 >> 24));
            float t0 = sqrtf(maxmd) * 1.0001f + S.w;
            thr = t0 * t0 * 1.0002f + 1e-12f;
        }
        __syncthreads();                    // the ONLY barrier per step

        // tree-structured 12-entry scan; winner wave from the key's chunk bits
        u64 a0 = wwin[par][0],  a1 = wwin[par][1],  a2  = wwin[par][2],  a3  = wwin[par][3];
        u64 a4 = wwin[par][4],  a5 = wwin[par][5],  a6  = wwin[par][6],  a7  = wwin[par][7];
        u64 a8 = wwin[par][8],  a9 = wwin[par][9],  a10 = wwin[par][10], a11 = wwin[par][11];
        u64 b0 = a0 > a1 ? a0 : a1;   u64 b1 = a2 > a3 ? a2 : a3;
        u64 b2 = a4 > a5 ? a4 : a5;   u64 b3 = a6 > a7 ? a6 : a7;
        u64 b4 = a8 > a9 ? a8 : a9;   u64 b5 = a10 > a11 ? a10 : a11;
        u64 e0 = b0 > b1 ? b0 : b1;   u64 e1 = b2 > b3 ? b2 : b3;
        u64 e2 = b4 > b5 ? b4 : b5;
        u64 e3 = e0 > e1 ? e0 : e1;
        u64 kb = e3 > e2 ? e3 : e2;
        int wb = ((int)(kb & 0x1FFull)) % NWAVE;
        float4 C4 = wcoord[par][wb];
        float ncx = C4.x, ncy = C4.y, ncz = C4.z;
        if (tid == 0) out_idx[s] = (int)(0x7FFFu - (u32)((kb >> 9) & 0x7FFFull));
        par ^= 1;

        // B: prune own chunk (registers only). Winner's chunk never pruned
        // (nc inside its own sphere).
        bool act = false;
        if (k0 != 0ull) {
            float Dx = ncx - S.x, Dy = ncy - S.y, Dz = ncz - S.z;
            float D2 = Dx * Dx + Dy * Dy + Dz * Dz;
            act = (D2 <= thr);
        }
        u64 m = __ballot(act);              // bit r -> chunk r*NWAVE+wv active

        // C: process active slots, all in registers. Static unroll keeps arrays
        // in VGPRs; all guards are wave-uniform branches.
        #pragma unroll
        for (int r = 0; r < NSLOT; ++r) {
            if ((m >> r) & 1ull) {
                float d = sq_dist_nofma(px[r], py[r], pz[r], ncx, ncy, ncz);
                bool chg = d < pmd[r];      // sentinels: pmd=0, never true
                u64 mchg = __ballot(chg);
                if (mchg) {
                    if (chg) pmd[r] = d;    // fmin(pmd,d) == d when chg
                    // mds only decrease: chunk max/winner can change only if the
                    // winner lane's own md decreased.
                    int wlo = __builtin_amdgcn_readlane(wlane, r);
                    if ((mchg >> wlo) & 1ull) {
                        u32 v  = __float_as_uint(pmd[r]);   // sentinels contribute 0
                        u32 mv = wave_max_u32(v);
                        u64 tb = __ballot(v == mv);
                        int wl; u32 low;
                        if (__popcll(tb) == 1) {            // unique winner (common)
                            wl = __ffsll(tb) - 1;
                            u32 pw = (u32)__builtin_amdgcn_readlane((int)po16[r / 2], wl);
                            u32 ow = (pw >> (16 * (r & 1))) & 0xFFFFu;
                            low = ((0x7FFFu - ow) << 9) | (u32)(r * NWAVE + wv);
                        } else {                            // exact md bit-tie (rare)
                            u32 o2 = (po16[r / 2] >> (16 * (r & 1))) & 0xFFFFu;
                            u32 pl = (v == mv && o2 != 0xFFFFu)
                                   ? (((0x7FFFu - o2) << 9) | (u32)(r * NWAVE + wv)) : 0u;
                            u32 t2 = wave_max_u32(pl);
                            wl = __ffsll(__ballot(pl == t2 && pl != 0u)) - 1;
                            low = t2;
                        }
                        float bx = __uint_as_float((u32)__builtin_amdgcn_readlane(__float_as_int(px[r]), wl));
                        float by = __uint_as_float((u32)__builtin_amdgcn_readlane(__float_as_int(py[r]), wl));
                        float bz = __uint_as_float((u32)__builtin_amdgcn_readlane(__float_as_int(pz[r]), wl));
                        if (lane == r) {    // deliver to owner lane (same wave)
                            k0 = ((u64)mv << 24) | low;
                            wx = bx; wy = by; wz = bz; wlane = wl;
                        }
                    }
                }
            }
        }
    }
}

// K5: ball query, one wave per dst. First K in-radius src indices in ascending order.
__global__ void ball_kernel(const float* __restrict__ sx, const float* __restrict__ sy,
                            const float* __restrict__ sz, const float* __restrict__ sn,
                            const int* __restrict__ idx,
                            const float* __restrict__ coord, const int* __restrict__ batch,
                            int N, int n_dst,
                            float* __restrict__ out_coord, float* __restrict__ out_esrc,
                            float* __restrict__ out_edst, float* __restrict__ out_deg,
                            float* __restrict__ out_batch,
                            int* __restrict__ nbr_i, int* __restrict__ deg_i) {
    const int d    = blockIdx.x;
    const int lane = threadIdx.x;   // block of 64
    __shared__ int nbr[KNBR];

    const int id = idx[d];
    const float cx = sx[id], cy = sy[id], cz = sz[id];
    const float dn = sn[id];
    const float RR = (float)(0.08 * 0.08);

    int cnt = 0;
    for (int base = 0; base < N && cnt < KNBR; base += 64) {
        int i = base + lane;
        bool in = false;
        if (i < N) {
            float t     = __fmul_rn(sx[i], cx);
            float inner = __fmaf_rn(sy[i], cy, t);
            inner       = __fmaf_rn(sz[i], cz, inner);
            float d2    = __fsub_rn(__fadd_rn(dn, sn[i]), __fmul_rn(2.0f, inner));
            in = (d2 <= RR);
        }
        unsigned long long m = __ballot(in);
        int pos = cnt + __popcll(m & ((1ull << lane) - 1ull));
        if (in && pos < KNBR) nbr[pos] = i;
        cnt += (int)__popcll(m);
    }
    __syncthreads();

    int deg = cnt < KNBR ? cnt : KNBR;
    if (lane < KNBR) {
        int e = (lane < deg) ? nbr[lane] : -1;
        out_esrc[d * KNBR + lane] = (float)e;
        out_edst[d * KNBR + lane] = (float)((lane < deg) ? d : -1);
        nbr_i[d * KNBR + lane] = e;
    }
    if (lane == 0) { out_deg[d] = (float)deg; deg_i[d] = deg; }
    if (lane < 3)  out_coord[d * 3 + lane] = coord[id * 3 + lane];
    if (lane == 3) out_batch[d] = (float)batch[id];
}

// K6: scatter-mean of gathered features. One block per dst, one thread per feature dim.
__global__ void agg_kernel(const float* __restrict__ feat,
                           const int* __restrict__ nbr_i, const int* __restrict__ deg_i,
                           int F, float* __restrict__ out_feat) {
    const int d = blockIdx.x;
    const int t = threadIdx.x;  // F threads
    const int deg = deg_i[d];
    float acc = 0.0f;
    for (int k = 0; k < deg; ++k) {
        int nb = nbr_i[d * KNBR + k];
        acc = __fadd_rn(acc, feat[nb * F + t]);
    }
    float den = (float)(deg > 0 ? deg : 1);
    out_feat[d * F + t] = acc / den;
}

extern "C" void kernel_launch(void* const* d_in, const int* in_sizes, int n_in,
                              void* d_out, int out_size, void* d_ws, size_t ws_size,
                              hipStream_t stream) {
    const float* coord = (const float*)d_in[0];
    const float* feat  = (const float*)d_in[1];
    const int*   batch = (const int*)d_in[2];

    const int N      = in_sizes[0] / 3;
    const int F      = in_sizes[1] / N;
    const int n_dst  = N / 4;                 // RATIO = 0.25
    const int nchunk = (N + 63) / 64;         // 313

    // workspace layout (pts 16B-aligned: 4N floats precede it; N=20000 -> 320000 B)
    float*  sx      = (float*)d_ws;
    float*  sy      = sx + N;
    float*  sz      = sy + N;
    float*  sn      = sz + N;
    float4* pts     = (float4*)(sn + N);      // FCAP packed points
    float4* spheres = pts + FCAP;             // MAXCHUNK
    float4* wxyz_g  = spheres + MAXCHUNK;     // MAXCHUNK winner coords
    float*  mdbuf   = (float*)(wxyz_g + MAXCHUNK);    // FCAP floats
    u64*    ckeys   = (u64*)(mdbuf + FCAP);   // MAXCHUNK (8B-aligned)
    int*    cell      = (int*)(ckeys + MAXCHUNK);
    int*    rank      = cell + N;
    int*    hist      = rank + N;
    int*    cellstart = hist + NCELL;
    int*    idx       = cellstart + NCELL;
    int*    nbr_i     = idx + n_dst;
    int*    deg_i     = nbr_i + n_dst * KNBR;

    // output layout (all float32), reference return order
    float* out     = (float*)d_out;
    float* o_coord = out;                         // n_dst*3
    float* o_feat  = o_coord + (size_t)n_dst * 3; // n_dst*F
    float* o_esrc  = o_feat  + (size_t)n_dst * F; // n_dst*K
    float* o_edst  = o_esrc  + (size_t)n_dst * KNBR;
    float* o_deg   = o_edst  + (size_t)n_dst * KNBR;
    float* o_batch = o_deg   + n_dst;

    hipMemsetAsync(hist, 0, NCELL * sizeof(int), stream);
    prep_kernel<<<(N + 255) / 256, 256, 0, stream>>>(coord, N, sx, sy, sz, sn,
                                                     cell, rank, hist);
    scan_kernel<<<1, 1024, 0, stream>>>(hist, cellstart);
    scatter_kernel<<<(N + 255) / 256, 256, 0, stream>>>(sx, sy, sz, cell, rank,
                                                        cellstart, N, pts);
    pad_kernel<<<(nchunk * 64 - N + 255) / 256, 256, 0, stream>>>(pts, N, nchunk * 64);
    init_chunk_kernel<<<nchunk, 64, 0, stream>>>(pts, coord, mdbuf, spheres, ckeys,
                                                 wxyz_g);
    fps_kernel<<<1, FT, 0, stream>>>(pts, coord, spheres, ckeys, wxyz_g,
                                     nchunk, n_dst, idx);
    ball_kernel<<<n_dst, 64, 0, stream>>>(sx, sy, sz, sn, idx, coord, batch, N, n_dst,
                                          o_coord, o_esrc, o_edst, o_deg, o_batch,
                                          nbr_i, deg_i);
    agg_kernel<<<n_dst, F, 0, stream>>>(feat, nbr_i, deg_i, F, o_feat);
}